// Round 15
// baseline (752.574 us; speedup 1.0000x reference)
//
#include <hip/hip_runtime.h>
#include <hip/hip_bf16.h>
#include <math.h>

// ---------------- problem constants ----------------
constexpr int kT    = 8192;          // tokens (4*2048)
constexpr int kD    = 1024;          // d_model
constexpr int kF    = 4096;          // d_ff
constexpr int kE    = 8;             // experts
constexpr int kN    = kT * 2;        // top-k dispatch count = 16384
constexpr int kCap  = 2048;          // ceil(1.0 * 16384 / 8)
constexpr int kECap = kE * kCap;     // 16384

constexpr int kRouterBlocks = kT / 4;                        // 2048
constexpr int kT13Blocks    = (kF / 64) * (kD / 64) * 16;    // 16384 (w1+w3)
constexpr int kT2Blocks     = (kD / 64) * (kF / 64) * 8;     // 8192  (w2)

typedef __attribute__((ext_vector_type(8))) short bf16x8;   // 8 bf16 (4 VGPR) MFMA A/B frag
typedef __attribute__((ext_vector_type(4))) float f32x4;    // MFMA C/D frag

// async global->LDS, 16B per lane; LDS dst must be wave-uniform (HW adds lane*16)
__device__ __forceinline__ void gload16(const __hip_bfloat16* g, __hip_bfloat16* l) {
  auto gp = (const __attribute__((address_space(1))) __hip_bfloat16*)g;
  auto lp = (__attribute__((address_space(3))) __hip_bfloat16*)l;
  __builtin_amdgcn_global_load_lds((const __attribute__((address_space(1))) void*)gp,
                                   (__attribute__((address_space(3))) void*)lp,
                                   16, 0, 0);
}

// entry sync: own stages landed + block sync
#define SYNC_VM0() do { __builtin_amdgcn_sched_barrier(0); \
  asm volatile("s_waitcnt vmcnt(0)" ::: "memory"); \
  __builtin_amdgcn_s_barrier(); \
  asm volatile("" ::: "memory"); } while (0)
// WAR barrier: all frag reads sampled into regs (lgkmcnt 0) before buffer overwrite
#define READ_BARRIER() do { __builtin_amdgcn_sched_barrier(0); \
  asm volatile("s_waitcnt lgkmcnt(0)" ::: "memory"); \
  __builtin_amdgcn_s_barrier(); \
  __builtin_amdgcn_sched_barrier(0); } while (0)

// ================= prep: router + ALL weight transposes in ONE launch =================
__device__ __forceinline__ void transpose_body(const float* __restrict__ s,
                                               __hip_bfloat16* __restrict__ d,
                                               int R, int C, int bx, int by) {
  __shared__ float tile[64][65];
  const int c0 = bx * 64, r0 = by * 64;
  const int tid = threadIdx.x;
  const int lr = tid >> 4, lc4 = (tid & 15) * 4;   // 16 rows/pass, 4 passes
#pragma unroll
  for (int p = 0; p < 4; ++p) {
    int r = p * 16 + lr;
    float4 v = *(const float4*)(s + (size_t)(r0 + r) * C + c0 + lc4);
    tile[r][lc4] = v.x; tile[r][lc4 + 1] = v.y; tile[r][lc4 + 2] = v.z; tile[r][lc4 + 3] = v.w;
  }
  __syncthreads();
  const int c = tid >> 2, rc = (tid & 3) * 16;     // out-row c, 16 r-elems
  union { __hip_bfloat16 h[16]; bf16x8 v[2]; } o;
#pragma unroll
  for (int i = 0; i < 16; ++i) o.h[i] = __float2bfloat16(tile[rc + i][c]);
  __hip_bfloat16* drow = d + (size_t)(c0 + c) * R + r0 + rc;
  *(bf16x8*)drow = o.v[0];
  *(bf16x8*)(drow + 8) = o.v[1];
}

__global__ __launch_bounds__(256)
void prep_kernel(const float* __restrict__ x, const float* __restrict__ rw,
                 const float* __restrict__ rb, int* __restrict__ e_idx,
                 float* __restrict__ gates, float* __restrict__ probs_out,
                 const float* __restrict__ w1, const float* __restrict__ w3,
                 const float* __restrict__ w2, __hip_bfloat16* __restrict__ w1t,
                 __hip_bfloat16* __restrict__ w3t, __hip_bfloat16* __restrict__ w2t) {
  int bid = blockIdx.x;
  if (bid < kRouterBlocks) {
    int t = bid * 4 + (threadIdx.x >> 6);
    int lane = threadIdx.x & 63;
    const float* xr = x + (size_t)t * kD;
    float acc[8];
#pragma unroll
    for (int e = 0; e < 8; ++e) acc[e] = 0.f;
    for (int i = 0; i < kD / 256; ++i) {
      int d = i * 256 + lane * 4;
      float4 xv = *(const float4*)(xr + d);
#pragma unroll
      for (int j = 0; j < 4; ++j) {
        float xs = (j == 0) ? xv.x : (j == 1) ? xv.y : (j == 2) ? xv.z : xv.w;
        const float4* w4 = (const float4*)(rw + (size_t)(d + j) * 8);
        float4 wa = w4[0], wb = w4[1];
        acc[0] += xs * wa.x; acc[1] += xs * wa.y; acc[2] += xs * wa.z; acc[3] += xs * wa.w;
        acc[4] += xs * wb.x; acc[5] += xs * wb.y; acc[6] += xs * wb.z; acc[7] += xs * wb.w;
      }
    }
#pragma unroll
    for (int off = 32; off >= 1; off >>= 1) {
#pragma unroll
      for (int e = 0; e < 8; ++e) acc[e] += __shfl_xor(acc[e], off);
    }
    if (lane == 0) {
      float l[8], m = -1e30f;
#pragma unroll
      for (int e = 0; e < 8; ++e) { l[e] = acc[e] + rb[e]; m = fmaxf(m, l[e]); }
      float p[8], s = 0.f;
#pragma unroll
      for (int e = 0; e < 8; ++e) { p[e] = __expf(l[e] - m); s += p[e]; }
      float inv = 1.f / s;
#pragma unroll
      for (int e = 0; e < 8; ++e) p[e] *= inv;
      int i1 = 0;
#pragma unroll
      for (int e = 1; e < 8; ++e) if (p[e] > p[i1]) i1 = e;   // strict >: ties -> lowest idx
      int i2 = (i1 == 0) ? 1 : 0;
#pragma unroll
      for (int e = 0; e < 8; ++e) if (e != i1 && e != i2 && p[e] > p[i2]) i2 = e;
      float den = fmaxf(p[i1] + p[i2], 1e-9f);
      e_idx[2 * t] = i1; e_idx[2 * t + 1] = i2;
      gates[2 * t] = p[i1] / den; gates[2 * t + 1] = p[i2] / den;
      float4* po = (float4*)(probs_out + (size_t)t * 8);
      po[0] = make_float4(p[0], p[1], p[2], p[3]);
      po[1] = make_float4(p[4], p[5], p[6], p[7]);
    }
    return;
  }
  const float* src; __hip_bfloat16* dst; int R, C, bx, by;
  bid -= kRouterBlocks;
  if (bid < kT13Blocks) {              // w1/w3
    bx = bid & 63; by = (bid >> 6) & 15;
    int z = bid >> 10;
    R = kD; C = kF;
    size_t mat = (size_t)kD * kF;
    src = ((z < 8) ? w1 : w3) + (size_t)(z & 7) * mat;
    dst = ((z < 8) ? w1t : w3t) + (size_t)(z & 7) * mat;
  } else {                             // w2
    bid -= kT13Blocks;
    bx = bid & 15; by = (bid >> 4) & 63;
    int e2 = bid >> 10;
    R = kF; C = kD;
    size_t mat = (size_t)kF * kD;
    src = w2 + (size_t)e2 * mat;
    dst = w2t + (size_t)e2 * mat;
  }
  transpose_body(src, dst, R, C, bx, by);
}

// ---------------- aux: importance/load reduction + aux loss (single block) ----------------
__global__ __launch_bounds__(1024)
void aux_kernel(const float* __restrict__ probs, const int* __restrict__ e_idx,
                float* __restrict__ aux_out) {
  int tid = threadIdx.x, lane = tid & 63, wave = tid >> 6;
  float imp[8];
  int cnt[8];
#pragma unroll
  for (int e = 0; e < 8; ++e) { imp[e] = 0.f; cnt[e] = 0; }
  for (int t = tid; t < kT; t += 1024) {
    const float4* p4 = (const float4*)(probs + (size_t)t * 8);
    float4 a = p4[0], b = p4[1];
    imp[0] += a.x; imp[1] += a.y; imp[2] += a.z; imp[3] += a.w;
    imp[4] += b.x; imp[5] += b.y; imp[6] += b.z; imp[7] += b.w;
    ++cnt[e_idx[2 * t] & 7];
  }
#pragma unroll
  for (int off = 32; off >= 1; off >>= 1) {
#pragma unroll
    for (int e = 0; e < 8; ++e) {
      imp[e] += __shfl_xor(imp[e], off);
      cnt[e] += __shfl_xor(cnt[e], off);
    }
  }
  __shared__ float simp[16][8];
  __shared__ int scnt[16][8];
  if (lane == 0) {
#pragma unroll
    for (int e = 0; e < 8; ++e) { simp[wave][e] = imp[e]; scnt[wave][e] = cnt[e]; }
  }
  __syncthreads();
  if (tid == 0) {
    float lb = 0.f;
    for (int e = 0; e < 8; ++e) {
      float I = 0.f; int C = 0;
      for (int w = 0; w < 16; ++w) { I += simp[w][e]; C += scnt[w][e]; }
      lb += (I / (float)kT) * ((float)C / (float)kT);
    }
    aux_out[0] = 0.01f * lb * (float)kE;   // Z_COEF == 0
  }
}

// ------- rank (fused: stable counting-rank + scatter + unused-slot init) -------
__global__ __launch_bounds__(256)
void rank_kernel(const int* __restrict__ e_idx, int* __restrict__ slot_of,
                 int* __restrict__ token_of) {
  int e = blockIdx.x;                 // one block per expert
  __shared__ int wave_sum[4];
  __shared__ int running;
  int tid = threadIdx.x, lane = tid & 63, wave = tid >> 6;
  if (tid == 0) running = 0;
  __syncthreads();
  for (int base = 0; base < kN; base += 256) {
    int i = base + tid;
    bool f = (e_idx[i] == e);
    unsigned long long m = __ballot(f);
    int wpre = __popcll(m & ((1ull << lane) - 1ull));
    if (lane == 0) wave_sum[wave] = __popcll(m);
    __syncthreads();
    int woff = 0;
    for (int w = 0; w < wave; ++w) woff += wave_sum[w];
    int r = running;
    if (f) {
      int p = r + woff + wpre;
      if (p < kCap) {
        slot_of[i] = e * kCap + p;     // kept slot
        token_of[e * kCap + p] = i >> 1;
      } else {
        slot_of[i] = -1;               // dropped (over capacity)
      }
    }
    __syncthreads();
    if (tid == 0) running = r + wave_sum[0] + wave_sum[1] + wave_sum[2] + wave_sum[3];
    __syncthreads();
  }
  // tail: unused slots -> -1
  for (int p = running + tid; p < kCap; p += 256)
    token_of[e * kCap + p] = -1;
}

// ---------------- gather: x rows -> bf16 expert buffer (zeros for unused slots) ----------------
struct __attribute__((aligned(8))) bf16x4s { __hip_bfloat16 v[4]; };

__global__ __launch_bounds__(64)
void gather_kernel(const float* __restrict__ x, const int* __restrict__ token_of,
                   __hip_bfloat16* __restrict__ buf) {
  int slot = blockIdx.x, lane = threadIdx.x;
  int t = token_of[slot];
  __hip_bfloat16* br = buf + (size_t)slot * kD;
  if (t >= 0) {
    const float* xr = x + (size_t)t * kD;
#pragma unroll
    for (int j = 0; j < 4; ++j) {
      int dd = (j * 64 + lane) * 4;
      float4 v = *(const float4*)(xr + dd);
      bf16x4s o;
      o.v[0] = __float2bfloat16(v.x); o.v[1] = __float2bfloat16(v.y);
      o.v[2] = __float2bfloat16(v.z); o.v[3] = __float2bfloat16(v.w);
      *(bf16x4s*)(br + dd) = o;
    }
  } else {
    bf16x4s z;
    z.v[0] = z.v[1] = z.v[2] = z.v[3] = __float2bfloat16(0.f);
#pragma unroll
    for (int j = 0; j < 4; ++j) *(bf16x4s*)(br + (j * 64 + lane) * 4) = z;
  }
}

// ================= GEMM1: h = silu(buf@w1) * (buf@w3) =================
// SINGLE-buffer 64KB (A[256][64] | B[256][64] swz) -> 2 blocks/CU; cross-block TLP
// hides staging+barrier stalls (m114 mechanism). Per tile: SYNC_VM0 -> read 24 frags
// -> lgkm0+barrier (WAR) -> issue t+1 stages -> 64 MFMA.
__global__ __launch_bounds__(512, 2)
void gemm1_kernel(const __hip_bfloat16* __restrict__ Abase,
                  const __hip_bfloat16* __restrict__ W1t,
                  const __hip_bfloat16* __restrict__ W3t,
                  __hip_bfloat16* __restrict__ H) {
  constexpr int K = kD;             // 1024
  constexpr int NT = K / 64;        // 16 K-tiles
  const int e = blockIdx.z, mt = blockIdx.y, ft = blockIdx.x;
  const int tid = threadIdx.x, lane = tid & 63, wave = tid >> 6;
  const int wr = wave >> 1, wc = wave & 1;   // 4M x 2N
  const int frow = lane & 15, fk = lane >> 4;

  const __hip_bfloat16* A  = Abase + (size_t)(e * kCap + mt * 256) * K;
  const __hip_bfloat16* B1 = W1t + ((size_t)e * kF + ft * 128) * K;
  const __hip_bfloat16* B3 = W3t + ((size_t)e * kF + ft * 128) * K;

  extern __shared__ __hip_bfloat16 lds[];   // 32768 elems = 64KB

  f32x4 accU[4][4], accV[4][4];
#pragma unroll
  for (int m = 0; m < 4; ++m)
#pragma unroll
    for (int n = 0; n < 4; ++n) {
      accU[m][n] = (f32x4){0.f, 0.f, 0.f, 0.f};
      accV[m][n] = (f32x4){0.f, 0.f, 0.f, 0.f};
    }

  auto stageA = [&](int t) {               // quarter wr, staged by waves (wr,*)
#pragma unroll
    for (int j = 0; j < 4; ++j) {
      int c = j * 128 + wc * 64 + lane;
      int rl = c >> 3, s = c & 7;
      const __hip_bfloat16* g = A + (size_t)(wr * 64 + rl) * K + t * 64 + (s ^ (rl & 7)) * 8;
      gload16(g, &lds[wr * 4096 + (j * 128 + wc * 64) * 8]);
    }
  };
  auto stageB1 = [&](int t) {              // w1 quarter wc, staged by waves (*,wc)
#pragma unroll
    for (int j = 0; j < 2; ++j) {
      int c = j * 256 + wr * 64 + lane;
      int rl = c >> 3, s = c & 7;
      const __hip_bfloat16* g = B1 + (size_t)(wc * 64 + rl) * K + t * 64 + (s ^ (rl & 7)) * 8;
      gload16(g, &lds[16384 + wc * 4096 + (j * 256 + wr * 64) * 8]);
    }
  };
  auto stageB3 = [&](int t) {              // w3 quarter wc (LDS rows 128+)
#pragma unroll
    for (int j = 0; j < 2; ++j) {
      int c = j * 256 + wr * 64 + lane;
      int rl = c >> 3, s = c & 7;
      const __hip_bfloat16* g = B3 + (size_t)(wc * 64 + rl) * K + t * 64 + (s ^ (rl & 7)) * 8;
      gload16(g, &lds[16384 + 8192 + wc * 4096 + (j * 256 + wr * 64) * 8]);
    }
  };

  // prologue: tile 0
  stageA(0); stageB1(0); stageB3(0);

  for (int t = 0; t < NT; ++t) {
    const bool nx = (t + 1 < NT);
    SYNC_VM0();                              // tile t landed, block synced

    bf16x8 af[4][2], bu[4][2], bv[4][2];
#pragma unroll
    for (int m = 0; m < 4; ++m)
#pragma unroll
      for (int h = 0; h < 2; ++h) {
        int row = wr * 64 + m * 16 + frow;
        af[m][h] = *(const bf16x8*)&lds[row * 64 + ((h * 4 + fk) ^ (row & 7)) * 8];
      }
#pragma unroll
    for (int n = 0; n < 4; ++n)
#pragma unroll
      for (int h = 0; h < 2; ++h) {
        int row = wc * 64 + n * 16 + frow;
        bu[n][h] = *(const bf16x8*)&lds[16384 + row * 64 + ((h * 4 + fk) ^ (row & 7)) * 8];
      }
#pragma unroll
    for (int n = 0; n < 4; ++n)
#pragma unroll
      for (int h = 0; h < 2; ++h) {
        int row = 128 + wc * 64 + n * 16 + frow;
        bv[n][h] = *(const bf16x8*)&lds[16384 + row * 64 + ((h * 4 + fk) ^ (row & 7)) * 8];
      }
    READ_BARRIER();                          // all reads in regs; safe to overwrite

    if (nx) { stageA(t + 1); stageB1(t + 1); stageB3(t + 1); }

    __builtin_amdgcn_s_setprio(1);
#pragma unroll
    for (int m = 0; m < 4; ++m)
#pragma unroll
      for (int n = 0; n < 4; ++n)
#pragma unroll
        for (int h = 0; h < 2; ++h)
          accU[m][n] = __builtin_amdgcn_mfma_f32_16x16x32_bf16(af[m][h], bu[n][h], accU[m][n], 0, 0, 0);
#pragma unroll
    for (int m = 0; m < 4; ++m)
#pragma unroll
      for (int n = 0; n < 4; ++n)
#pragma unroll
        for (int h = 0; h < 2; ++h)
          accV[m][n] = __builtin_amdgcn_mfma_f32_16x16x32_bf16(af[m][h], bv[n][h], accV[m][n], 0, 0, 0);
    __builtin_amdgcn_s_setprio(0);
    __builtin_amdgcn_sched_barrier(0);
  }

  // epilogue: h = silu(u) * v
  __hip_bfloat16* Ht = H + (size_t)(e * kCap + mt * 256) * kF + ft * 128;
#pragma unroll
  for (int m = 0; m < 4; ++m)
#pragma unroll
    for (int n = 0; n < 4; ++n)
#pragma unroll
      for (int r = 0; r < 4; ++r) {
        int row = wr * 64 + m * 16 + fk * 4 + r;   // C/D: col=lane&15, row=(lane>>4)*4+reg
        int col = wc * 64 + n * 16 + frow;
        float u = accU[m][n][r], v = accV[m][n][r];
        float hval = (u / (1.f + __expf(-u))) * v;
        Ht[(size_t)row * kF + col] = __float2bfloat16(hval);
      }
}

// ================= GEMM2: y = h @ w2 (bf16 output) =================
// SINGLE-buffer 64KB (A[256][64] | B[256][64] swz) -> 2 blocks/CU; same schedule
__global__ __launch_bounds__(512, 2)
void gemm2_kernel(const __hip_bfloat16* __restrict__ Hbase,
                  const __hip_bfloat16* __restrict__ W2t,
                  __hip_bfloat16* __restrict__ Y) {
  constexpr int K = kF;             // 4096
  constexpr int NT = K / 64;        // 64 K-tiles
  const int e = blockIdx.z, mt = blockIdx.y, nt = blockIdx.x;
  const int tid = threadIdx.x, lane = tid & 63, wave = tid >> 6;
  const int wr = wave >> 2, wc = wave & 3;   // 2M x 4N
  const int frow = lane & 15, fk = lane >> 4;

  const __hip_bfloat16* A = Hbase + (size_t)(e * kCap + mt * 256) * K;
  const __hip_bfloat16* B = W2t + ((size_t)e * kD + nt * 256) * K;

  extern __shared__ __hip_bfloat16 lds[];

  f32x4 acc[2][4][4];
#pragma unroll
  for (int p = 0; p < 2; ++p)
#pragma unroll
    for (int m = 0; m < 4; ++m)
#pragma unroll
      for (int n = 0; n < 4; ++n) acc[p][m][n] = (f32x4){0.f, 0.f, 0.f, 0.f};

  auto stageB = [&](int t) {               // B quarter wc
#pragma unroll
    for (int j = 0; j < 4; ++j) {
      int c = j * 128 + wr * 64 + lane;
      int rl = c >> 3, s = c & 7;
      const __hip_bfloat16* g = B + (size_t)(wc * 64 + rl) * K + t * 64 + (s ^ (rl & 7)) * 8;
      gload16(g, &lds[16384 + wc * 4096 + (j * 128 + wr * 64) * 8]);
    }
  };
  auto stageA = [&](int t, int p) {        // A quarter 2wr+p
    int q = 2 * wr + p;
#pragma unroll
    for (int j = 0; j < 2; ++j) {
      int c = j * 256 + wc * 64 + lane;
      int rl = c >> 3, s = c & 7;
      const __hip_bfloat16* g = A + (size_t)(q * 64 + rl) * K + t * 64 + (s ^ (rl & 7)) * 8;
      gload16(g, &lds[q * 4096 + (j * 256 + wc * 64) * 8]);
    }
  };

  stageB(0); stageA(0, 0); stageA(0, 1);

  for (int t = 0; t < NT; ++t) {
    const bool nx = (t + 1 < NT);
    SYNC_VM0();

    bf16x8 bf[4][2], a0[4][2], a1[4][2];
#pragma unroll
    for (int n = 0; n < 4; ++n)
#pragma unroll
      for (int h = 0; h < 2; ++h) {
        int row = wc * 64 + n * 16 + frow;
        bf[n][h] = *(const bf16x8*)&lds[16384 + row * 64 + ((h * 4 + fk) ^ (row & 7)) * 8];
      }
#pragma unroll
    for (int m = 0; m < 4; ++m)
#pragma unroll
      for (int h = 0; h < 2; ++h) {
        int row = wr * 128 + m * 16 + frow;
        a0[m][h] = *(const bf16x8*)&lds[row * 64 + ((h * 4 + fk) ^ (row & 7)) * 8];
      }
#pragma unroll
    for (int m = 0; m < 4; ++m)
#pragma unroll
      for (int h = 0; h < 2; ++h) {
        int row = wr * 128 + 64 + m * 16 + frow;
        a1[m][h] = *(const bf16x8*)&lds[row * 64 + ((h * 4 + fk) ^ (row & 7)) * 8];
      }
    READ_BARRIER();

    if (nx) { stageB(t + 1); stageA(t + 1, 0); stageA(t + 1, 1); }

    __builtin_amdgcn_s_setprio(1);
#pragma unroll
    for (int m = 0; m < 4; ++m)
#pragma unroll
      for (int n = 0; n < 4; ++n)
#pragma unroll
        for (int h = 0; h < 2; ++h)
          acc[0][m][n] = __builtin_amdgcn_mfma_f32_16x16x32_bf16(a0[m][h], bf[n][h], acc[0][m][n], 0, 0, 0);
#pragma unroll
    for (int m = 0; m < 4; ++m)
#pragma unroll
      for (int n = 0; n < 4; ++n)
#pragma unroll
        for (int h = 0; h < 2; ++h)
          acc[1][m][n] = __builtin_amdgcn_mfma_f32_16x16x32_bf16(a1[m][h], bf[n][h], acc[1][m][n], 0, 0, 0);
    __builtin_amdgcn_s_setprio(0);
    __builtin_amdgcn_sched_barrier(0);
  }

  __hip_bfloat16* Yt = Y + (size_t)(e * kCap + mt * 256) * kD + nt * 256;
#pragma unroll
  for (int p = 0; p < 2; ++p)
#pragma unroll
    for (int m = 0; m < 4; ++m)
#pragma unroll
      for (int n = 0; n < 4; ++n)
#pragma unroll
        for (int r = 0; r < 4; ++r) {
          int row = wr * 128 + p * 64 + m * 16 + fk * 4 + r;
          int col = wc * 64 + n * 16 + frow;
          Yt[(size_t)row * kD + col] = __float2bfloat16(acc[p][m][n][r]);
        }
}

// ---------------- combine: out[t] = sum_k gate * y[slot] (deterministic gather, bf16 y) ----
__global__ __launch_bounds__(256)
void combine_kernel(const __hip_bfloat16* __restrict__ Y, const int* __restrict__ slot_of,
                    const float* __restrict__ gates, float* __restrict__ out) {
  int t = blockIdx.x;
  int dd = threadIdx.x * 4;
  int s0 = slot_of[2 * t], s1 = slot_of[2 * t + 1];
  float g0 = gates[2 * t], g1 = gates[2 * t + 1];
  float4 r = {0.f, 0.f, 0.f, 0.f};
  if (s0 >= 0) {
    bf16x4s v = *(const bf16x4s*)(Y + (size_t)s0 * kD + dd);
    r.x += g0 * __bfloat162float(v.v[0]); r.y += g0 * __bfloat162float(v.v[1]);
    r.z += g0 * __bfloat162float(v.v[2]); r.w += g0 * __bfloat162float(v.v[3]);
  }
  if (s1 >= 0) {
    bf16x4s v = *(const bf16x4s*)(Y + (size_t)s1 * kD + dd);
    r.x += g1 * __bfloat162float(v.v[0]); r.y += g1 * __bfloat162float(v.v[1]);
    r.z += g1 * __bfloat162float(v.v[2]); r.w += g1 * __bfloat162float(v.v[3]);
  }
  *(float4*)(out + (size_t)t * kD + dd) = r;
}

// ---------------- host launcher ----------------
extern "C" void kernel_launch(void* const* d_in, const int* in_sizes, int n_in,
                              void* d_out, int out_size, void* d_ws, size_t ws_size,
                              hipStream_t stream) {
  (void)in_sizes; (void)n_in; (void)out_size; (void)ws_size;
  const float* x  = (const float*)d_in[0];
  const float* rw = (const float*)d_in[1];
  const float* rb = (const float*)d_in[2];
  const float* w1 = (const float*)d_in[3];
  const float* w3 = (const float*)d_in[4];
  const float* w2 = (const float*)d_in[5];
  float* out = (float*)d_out;

  char* base = (char*)d_ws;
  size_t off = 0;
  auto alloc = [&](size_t bytes) -> char* {
    char* r = base + off;
    off += (bytes + 255) & ~(size_t)255;
    return r;
  };
  __hip_bfloat16* w1t = (__hip_bfloat16*)alloc((size_t)kE * kF * kD * 2);  // [E][F][D]
  __hip_bfloat16* w3t = (__hip_bfloat16*)alloc((size_t)kE * kF * kD * 2);  // [E][F][D]
  __hip_bfloat16* w2t = (__hip_bfloat16*)alloc((size_t)kE * kD * kF * 2);  // [E][D][F]
  __hip_bfloat16* buf = (__hip_bfloat16*)alloc((size_t)kECap * kD * 2);
  __hip_bfloat16* h   = (__hip_bfloat16*)alloc((size_t)kECap * kF * 2);
  __hip_bfloat16* y   = (__hip_bfloat16*)alloc((size_t)kECap * kD * 2);
  int*   e_idx    = (int*)alloc((size_t)kN * 4);
  float* gates    = (float*)alloc((size_t)kN * 4);
  int*   slot_of  = (int*)alloc((size_t)kN * 4);
  int*   token_of = (int*)alloc((size_t)kECap * 4);
  float* probs    = (float*)alloc((size_t)kT * 8 * 4);

  prep_kernel<<<kRouterBlocks + kT13Blocks + kT2Blocks, 256, 0, stream>>>(
      x, rw, rb, e_idx, gates, probs, w1, w3, w2, w1t, w3t, w2t);
  aux_kernel<<<1, 1024, 0, stream>>>(probs, e_idx, out + (size_t)kT * kD);
  rank_kernel<<<kE, 256, 0, stream>>>(e_idx, slot_of, token_of);
  gather_kernel<<<kECap, 64, 0, stream>>>(x, token_of, buf);
  gemm1_kernel<<<dim3(kF / 128, kCap / 256, kE), 512, 65536, stream>>>(buf, w1t, w3t, h);
  gemm2_kernel<<<dim3(kD / 256, kCap / 256, kE), 512, 65536, stream>>>(h, w2t, y);
  combine_kernel<<<kT, 256, 0, stream>>>(y, slot_of, gates, out);
}

// Round 16
// 601.016 us; speedup vs baseline: 1.2522x; 1.2522x over previous
//
#include <hip/hip_runtime.h>
#include <hip/hip_bf16.h>
#include <math.h>

// ---------------- problem constants ----------------
constexpr int kT    = 8192;          // tokens (4*2048)
constexpr int kD    = 1024;          // d_model
constexpr int kF    = 4096;          // d_ff
constexpr int kE    = 8;             // experts
constexpr int kN    = kT * 2;        // top-k dispatch count = 16384
constexpr int kCap  = 2048;          // ceil(1.0 * 16384 / 8)
constexpr int kECap = kE * kCap;     // 16384

constexpr int kRouterBlocks = kT / 4;                        // 2048
constexpr int kT13Blocks    = (kF / 64) * (kD / 64) * 16;    // 16384 (w1+w3)
constexpr int kT2Blocks     = (kD / 64) * (kF / 64) * 8;     // 8192  (w2)

typedef __attribute__((ext_vector_type(8))) short bf16x8;   // 8 bf16 (4 VGPR) MFMA A/B frag
typedef __attribute__((ext_vector_type(4))) float f32x4;    // MFMA C/D frag

// async global->LDS, 16B per lane; LDS dst must be wave-uniform (HW adds lane*16)
__device__ __forceinline__ void gload16(const __hip_bfloat16* g, __hip_bfloat16* l) {
  auto gp = (const __attribute__((address_space(1))) __hip_bfloat16*)g;
  auto lp = (__attribute__((address_space(3))) __hip_bfloat16*)l;
  __builtin_amdgcn_global_load_lds((const __attribute__((address_space(1))) void*)gp,
                                   (__attribute__((address_space(3))) void*)lp,
                                   16, 0, 0);
}

// sync points: pin schedule, counted vmcnt, raw barrier (no compiler drain)
#define SYNC_VM(N) do { __builtin_amdgcn_sched_barrier(0); \
  asm volatile("s_waitcnt vmcnt(" #N ")" ::: "memory"); \
  __builtin_amdgcn_s_barrier(); \
  asm volatile("" ::: "memory"); } while (0)

// ================= prep: router + ALL weight transposes in ONE launch =================
__device__ __forceinline__ void transpose_body(const float* __restrict__ s,
                                               __hip_bfloat16* __restrict__ d,
                                               int R, int C, int bx, int by) {
  __shared__ float tile[64][65];
  const int c0 = bx * 64, r0 = by * 64;
  const int tid = threadIdx.x;
  const int lr = tid >> 4, lc4 = (tid & 15) * 4;   // 16 rows/pass, 4 passes
#pragma unroll
  for (int p = 0; p < 4; ++p) {
    int r = p * 16 + lr;
    float4 v = *(const float4*)(s + (size_t)(r0 + r) * C + c0 + lc4);
    tile[r][lc4] = v.x; tile[r][lc4 + 1] = v.y; tile[r][lc4 + 2] = v.z; tile[r][lc4 + 3] = v.w;
  }
  __syncthreads();
  const int c = tid >> 2, rc = (tid & 3) * 16;     // out-row c, 16 r-elems
  union { __hip_bfloat16 h[16]; bf16x8 v[2]; } o;
#pragma unroll
  for (int i = 0; i < 16; ++i) o.h[i] = __float2bfloat16(tile[rc + i][c]);
  __hip_bfloat16* drow = d + (size_t)(c0 + c) * R + r0 + rc;
  *(bf16x8*)drow = o.v[0];
  *(bf16x8*)(drow + 8) = o.v[1];
}

__global__ __launch_bounds__(256)
void prep_kernel(const float* __restrict__ x, const float* __restrict__ rw,
                 const float* __restrict__ rb, int* __restrict__ e_idx,
                 float* __restrict__ gates, float* __restrict__ probs_out,
                 const float* __restrict__ w1, const float* __restrict__ w3,
                 const float* __restrict__ w2, __hip_bfloat16* __restrict__ w1t,
                 __hip_bfloat16* __restrict__ w3t, __hip_bfloat16* __restrict__ w2t) {
  int bid = blockIdx.x;
  if (bid < kRouterBlocks) {
    // ---- router role: fp32 logits, softmax, top-2, gates; probs -> ws ----
    int t = bid * 4 + (threadIdx.x >> 6);
    int lane = threadIdx.x & 63;
    const float* xr = x + (size_t)t * kD;
    float acc[8];
#pragma unroll
    for (int e = 0; e < 8; ++e) acc[e] = 0.f;
    for (int i = 0; i < kD / 256; ++i) {
      int d = i * 256 + lane * 4;
      float4 xv = *(const float4*)(xr + d);
#pragma unroll
      for (int j = 0; j < 4; ++j) {
        float xs = (j == 0) ? xv.x : (j == 1) ? xv.y : (j == 2) ? xv.z : xv.w;
        const float4* w4 = (const float4*)(rw + (size_t)(d + j) * 8);
        float4 wa = w4[0], wb = w4[1];
        acc[0] += xs * wa.x; acc[1] += xs * wa.y; acc[2] += xs * wa.z; acc[3] += xs * wa.w;
        acc[4] += xs * wb.x; acc[5] += xs * wb.y; acc[6] += xs * wb.z; acc[7] += xs * wb.w;
      }
    }
#pragma unroll
    for (int off = 32; off >= 1; off >>= 1) {
#pragma unroll
      for (int e = 0; e < 8; ++e) acc[e] += __shfl_xor(acc[e], off);
    }
    if (lane == 0) {
      float l[8], m = -1e30f;
#pragma unroll
      for (int e = 0; e < 8; ++e) { l[e] = acc[e] + rb[e]; m = fmaxf(m, l[e]); }
      float p[8], s = 0.f;
#pragma unroll
      for (int e = 0; e < 8; ++e) { p[e] = __expf(l[e] - m); s += p[e]; }
      float inv = 1.f / s;
#pragma unroll
      for (int e = 0; e < 8; ++e) p[e] *= inv;
      int i1 = 0;
#pragma unroll
      for (int e = 1; e < 8; ++e) if (p[e] > p[i1]) i1 = e;   // strict >: ties -> lowest idx
      int i2 = (i1 == 0) ? 1 : 0;
#pragma unroll
      for (int e = 0; e < 8; ++e) if (e != i1 && e != i2 && p[e] > p[i2]) i2 = e;
      float den = fmaxf(p[i1] + p[i2], 1e-9f);
      e_idx[2 * t] = i1; e_idx[2 * t + 1] = i2;
      gates[2 * t] = p[i1] / den; gates[2 * t + 1] = p[i2] / den;
      float4* po = (float4*)(probs_out + (size_t)t * 8);
      po[0] = make_float4(p[0], p[1], p[2], p[3]);
      po[1] = make_float4(p[4], p[5], p[6], p[7]);
    }
    return;
  }
  // ---- transpose roles ----
  const float* src; __hip_bfloat16* dst; int R, C, bx, by;
  bid -= kRouterBlocks;
  if (bid < kT13Blocks) {              // w1/w3: grid (64,16,16) flattened
    bx = bid & 63; by = (bid >> 6) & 15;
    int z = bid >> 10;                 // 0..15: 0-7 -> w1, 8-15 -> w3
    R = kD; C = kF;
    size_t mat = (size_t)kD * kF;
    src = ((z < 8) ? w1 : w3) + (size_t)(z & 7) * mat;
    dst = ((z < 8) ? w1t : w3t) + (size_t)(z & 7) * mat;
  } else {                             // w2: grid (16,64,8) flattened
    bid -= kT13Blocks;
    bx = bid & 15; by = (bid >> 4) & 63;
    int e2 = bid >> 10;
    R = kF; C = kD;
    size_t mat = (size_t)kF * kD;
    src = w2 + (size_t)e2 * mat;
    dst = w2t + (size_t)e2 * mat;
  }
  transpose_body(src, dst, R, C, bx, by);
}

// ---------------- aux: importance/load reduction + aux loss (single block) ----------------
__global__ __launch_bounds__(1024)
void aux_kernel(const float* __restrict__ probs, const int* __restrict__ e_idx,
                float* __restrict__ aux_out) {
  int tid = threadIdx.x, lane = tid & 63, wave = tid >> 6;
  float imp[8];
  int cnt[8];
#pragma unroll
  for (int e = 0; e < 8; ++e) { imp[e] = 0.f; cnt[e] = 0; }
  for (int t = tid; t < kT; t += 1024) {
    const float4* p4 = (const float4*)(probs + (size_t)t * 8);
    float4 a = p4[0], b = p4[1];
    imp[0] += a.x; imp[1] += a.y; imp[2] += a.z; imp[3] += a.w;
    imp[4] += b.x; imp[5] += b.y; imp[6] += b.z; imp[7] += b.w;
    ++cnt[e_idx[2 * t] & 7];
  }
#pragma unroll
  for (int off = 32; off >= 1; off >>= 1) {
#pragma unroll
    for (int e = 0; e < 8; ++e) {
      imp[e] += __shfl_xor(imp[e], off);
      cnt[e] += __shfl_xor(cnt[e], off);
    }
  }
  __shared__ float simp[16][8];
  __shared__ int scnt[16][8];
  if (lane == 0) {
#pragma unroll
    for (int e = 0; e < 8; ++e) { simp[wave][e] = imp[e]; scnt[wave][e] = cnt[e]; }
  }
  __syncthreads();
  if (tid == 0) {
    float lb = 0.f;
    for (int e = 0; e < 8; ++e) {
      float I = 0.f; int C = 0;
      for (int w = 0; w < 16; ++w) { I += simp[w][e]; C += scnt[w][e]; }
      lb += (I / (float)kT) * ((float)C / (float)kT);
    }
    aux_out[0] = 0.01f * lb * (float)kE;   // Z_COEF == 0
  }
}

// ------- rank (fused: stable counting-rank + scatter + unused-slot init) -------
__global__ __launch_bounds__(256)
void rank_kernel(const int* __restrict__ e_idx, int* __restrict__ slot_of,
                 int* __restrict__ token_of) {
  int e = blockIdx.x;                 // one block per expert
  __shared__ int wave_sum[4];
  __shared__ int running;
  int tid = threadIdx.x, lane = tid & 63, wave = tid >> 6;
  if (tid == 0) running = 0;
  __syncthreads();
  for (int base = 0; base < kN; base += 256) {
    int i = base + tid;
    bool f = (e_idx[i] == e);
    unsigned long long m = __ballot(f);
    int wpre = __popcll(m & ((1ull << lane) - 1ull));
    if (lane == 0) wave_sum[wave] = __popcll(m);
    __syncthreads();
    int woff = 0;
    for (int w = 0; w < wave; ++w) woff += wave_sum[w];
    int r = running;
    if (f) {
      int p = r + woff + wpre;
      if (p < kCap) {
        slot_of[i] = e * kCap + p;     // kept slot
        token_of[e * kCap + p] = i >> 1;
      } else {
        slot_of[i] = -1;               // dropped (over capacity)
      }
    }
    __syncthreads();
    if (tid == 0) running = r + wave_sum[0] + wave_sum[1] + wave_sum[2] + wave_sum[3];
    __syncthreads();
  }
  // tail: unused slots -> -1 (replaces init_kernel)
  for (int p = running + tid; p < kCap; p += 256)
    token_of[e * kCap + p] = -1;
}

// ---------------- gather: x rows -> bf16 expert buffer (zeros for unused slots) ----------------
struct __attribute__((aligned(8))) bf16x4s { __hip_bfloat16 v[4]; };

__global__ __launch_bounds__(64)
void gather_kernel(const float* __restrict__ x, const int* __restrict__ token_of,
                   __hip_bfloat16* __restrict__ buf) {
  int slot = blockIdx.x, lane = threadIdx.x;
  int t = token_of[slot];
  __hip_bfloat16* br = buf + (size_t)slot * kD;
  if (t >= 0) {
    const float* xr = x + (size_t)t * kD;
#pragma unroll
    for (int j = 0; j < 4; ++j) {
      int dd = (j * 64 + lane) * 4;
      float4 v = *(const float4*)(xr + dd);
      bf16x4s o;
      o.v[0] = __float2bfloat16(v.x); o.v[1] = __float2bfloat16(v.y);
      o.v[2] = __float2bfloat16(v.z); o.v[3] = __float2bfloat16(v.w);
      *(bf16x4s*)(br + dd) = o;
    }
  } else {
    bf16x4s z;
    z.v[0] = z.v[1] = z.v[2] = z.v[3] = __float2bfloat16(0.f);
#pragma unroll
    for (int j = 0; j < 4; ++j) *(bf16x4s*)(br + (j * 64 + lane) * 4) = z;
  }
}

// ================= GEMM1: h = silu(buf@w1) * (buf@w3) =================
// R5/R7 proven structure: tile 256M x 128F, BK=64, 8 waves 4M x 2N, wave 64x64 dual (U,V)
// swz LDS; per-tile issue [A(4), B1(2), B3(2)] reader-aligned; SYNC vmcnt(2), MID vmcnt(4)
__global__ __launch_bounds__(512, 2)
void gemm1_kernel(const __hip_bfloat16* __restrict__ Abase,
                  const __hip_bfloat16* __restrict__ W1t,
                  const __hip_bfloat16* __restrict__ W3t,
                  __hip_bfloat16* __restrict__ H) {
  constexpr int K = kD;             // 1024
  constexpr int NT = K / 64;        // 16 K-tiles
  const int e = blockIdx.z, mt = blockIdx.y, ft = blockIdx.x;
  const int tid = threadIdx.x, lane = tid & 63, wave = tid >> 6;
  const int wr = wave >> 1, wc = wave & 1;   // 4M x 2N
  const int frow = lane & 15, fk = lane >> 4;

  const __hip_bfloat16* A  = Abase + (size_t)(e * kCap + mt * 256) * K;
  const __hip_bfloat16* B1 = W1t + ((size_t)e * kF + ft * 128) * K;
  const __hip_bfloat16* B3 = W3t + ((size_t)e * kF + ft * 128) * K;

  extern __shared__ __hip_bfloat16 lds[];   // 2 x 32768 elems

  f32x4 accU[4][4], accV[4][4];
#pragma unroll
  for (int m = 0; m < 4; ++m)
#pragma unroll
    for (int n = 0; n < 4; ++n) {
      accU[m][n] = (f32x4){0.f, 0.f, 0.f, 0.f};
      accV[m][n] = (f32x4){0.f, 0.f, 0.f, 0.f};
    }

  auto stageA = [&](int t, int b) {        // quarter wr, staged by waves (wr,*)
#pragma unroll
    for (int j = 0; j < 4; ++j) {
      int c = j * 128 + wc * 64 + lane;
      int rl = c >> 3, s = c & 7;
      const __hip_bfloat16* g = A + (size_t)(wr * 64 + rl) * K + t * 64 + (s ^ (rl & 7)) * 8;
      gload16(g, &lds[b * 32768 + wr * 4096 + (j * 128 + wc * 64) * 8]);
    }
  };
  auto stageB1 = [&](int t, int b) {       // w1 quarter wc, staged by waves (*,wc)
#pragma unroll
    for (int j = 0; j < 2; ++j) {
      int c = j * 256 + wr * 64 + lane;
      int rl = c >> 3, s = c & 7;
      const __hip_bfloat16* g = B1 + (size_t)(wc * 64 + rl) * K + t * 64 + (s ^ (rl & 7)) * 8;
      gload16(g, &lds[b * 32768 + 16384 + wc * 4096 + (j * 256 + wr * 64) * 8]);
    }
  };
  auto stageB3 = [&](int t, int b) {       // w3 quarter wc (LDS rows 128+)
#pragma unroll
    for (int j = 0; j < 2; ++j) {
      int c = j * 256 + wr * 64 + lane;
      int rl = c >> 3, s = c & 7;
      const __hip_bfloat16* g = B3 + (size_t)(wc * 64 + rl) * K + t * 64 + (s ^ (rl & 7)) * 8;
      gload16(g, &lds[b * 32768 + 16384 + 8192 + wc * 4096 + (j * 256 + wr * 64) * 8]);
    }
  };
  auto phase = [&](int b, f32x4 (&ac)[4][4], bf16x8 (&af)[4][2], int broff, bool loadA) {
    if (loadA) {
#pragma unroll
      for (int m = 0; m < 4; ++m)
#pragma unroll
        for (int h = 0; h < 2; ++h) {
          int row = wr * 64 + m * 16 + frow;
          af[m][h] = *(const bf16x8*)&lds[b * 32768 + row * 64 + ((h * 4 + fk) ^ (row & 7)) * 8];
        }
    }
    bf16x8 bf[4][2];
#pragma unroll
    for (int n = 0; n < 4; ++n)
#pragma unroll
      for (int h = 0; h < 2; ++h) {
        int row = broff + wc * 64 + n * 16 + frow;
        bf[n][h] = *(const bf16x8*)&lds[b * 32768 + 16384 + row * 64 + ((h * 4 + fk) ^ (row & 7)) * 8];
      }
    __builtin_amdgcn_s_setprio(1);
#pragma unroll
    for (int m = 0; m < 4; ++m)
#pragma unroll
      for (int n = 0; n < 4; ++n)
#pragma unroll
        for (int h = 0; h < 2; ++h)
          ac[m][n] = __builtin_amdgcn_mfma_f32_16x16x32_bf16(af[m][h], bf[n][h], ac[m][n], 0, 0, 0);
    __builtin_amdgcn_s_setprio(0);
    __builtin_amdgcn_sched_barrier(0);
  };

  // prologue: tile 0, order [A, B1, B3]
  stageA(0, 0); stageB1(0, 0); stageB3(0, 0);

  for (int t = 0; t < NT; ++t) {
    const int b = t & 1, nb = b ^ 1;
    const bool nx = (t + 1 < NT);
    SYNC_VM(2);                              // A(t), B1(t) landed; B3(t) may be in flight
    if (nx) stageA(t + 1, nb);
    bf16x8 af[4][2];
    phase(b, accU, af, 0, true);             // U
    if (nx) { SYNC_VM(4); } else { SYNC_VM(0); }   // B3(t) landed
    if (nx) stageB1(t + 1, nb);
    phase(b, accV, af, 128, false);          // V
    if (nx) stageB3(t + 1, nb);
  }

  // epilogue: h = silu(u) * v
  __hip_bfloat16* Ht = H + (size_t)(e * kCap + mt * 256) * kF + ft * 128;
#pragma unroll
  for (int m = 0; m < 4; ++m)
#pragma unroll
    for (int n = 0; n < 4; ++n)
#pragma unroll
      for (int r = 0; r < 4; ++r) {
        int row = wr * 64 + m * 16 + fk * 4 + r;   // C/D: col=lane&15, row=(lane>>4)*4+reg
        int col = wc * 64 + n * 16 + frow;
        float u = accU[m][n][r], v = accV[m][n][r];
        float hval = (u / (1.f + __expf(-u))) * v;
        Ht[(size_t)row * kF + col] = __float2bfloat16(hval);
      }
}

// ================= GEMM2: y = h @ w2 (bf16 output) =================
// tile 256M x 256N, BK=64, 8 waves 2M x 4N, wave 128x64; swz LDS; R5/R7 sync pattern
__global__ __launch_bounds__(512, 2)
void gemm2_kernel(const __hip_bfloat16* __restrict__ Hbase,
                  const __hip_bfloat16* __restrict__ W2t,
                  __hip_bfloat16* __restrict__ Y) {
  constexpr int K = kF;             // 4096
  constexpr int NT = K / 64;        // 64 K-tiles
  const int e = blockIdx.z, mt = blockIdx.y, nt = blockIdx.x;
  const int tid = threadIdx.x, lane = tid & 63, wave = tid >> 6;
  const int wr = wave >> 2, wc = wave & 3;   // 2M x 4N
  const int frow = lane & 15, fk = lane >> 4;

  const __hip_bfloat16* A = Hbase + (size_t)(e * kCap + mt * 256) * K;
  const __hip_bfloat16* B = W2t + ((size_t)e * kD + nt * 256) * K;

  extern __shared__ __hip_bfloat16 lds[];

  f32x4 acc[2][4][4];
#pragma unroll
  for (int p = 0; p < 2; ++p)
#pragma unroll
    for (int m = 0; m < 4; ++m)
#pragma unroll
      for (int n = 0; n < 4; ++n) acc[p][m][n] = (f32x4){0.f, 0.f, 0.f, 0.f};

  auto stageB = [&](int t, int b) {        // B quarter wc
#pragma unroll
    for (int j = 0; j < 4; ++j) {
      int c = j * 128 + wr * 64 + lane;
      int rl = c >> 3, s = c & 7;
      const __hip_bfloat16* g = B + (size_t)(wc * 64 + rl) * K + t * 64 + (s ^ (rl & 7)) * 8;
      gload16(g, &lds[b * 32768 + 16384 + wc * 4096 + (j * 128 + wr * 64) * 8]);
    }
  };
  auto stageA = [&](int t, int p, int b) { // A quarter 2wr+p
    int q = 2 * wr + p;
#pragma unroll
    for (int j = 0; j < 2; ++j) {
      int c = j * 256 + wc * 64 + lane;
      int rl = c >> 3, s = c & 7;
      const __hip_bfloat16* g = A + (size_t)(q * 64 + rl) * K + t * 64 + (s ^ (rl & 7)) * 8;
      gload16(g, &lds[b * 32768 + q * 4096 + (j * 256 + wc * 64) * 8]);
    }
  };
  auto phase = [&](int b, int p, f32x4 (&ac)[4][4], bf16x8 (&bf)[4][2], bool loadB) {
    bf16x8 a[4][2];
#pragma unroll
    for (int m = 0; m < 4; ++m)
#pragma unroll
      for (int h = 0; h < 2; ++h) {
        int row = wr * 128 + p * 64 + m * 16 + frow;
        a[m][h] = *(const bf16x8*)&lds[b * 32768 + row * 64 + ((h * 4 + fk) ^ (row & 7)) * 8];
      }
    if (loadB) {
#pragma unroll
      for (int n = 0; n < 4; ++n)
#pragma unroll
        for (int h = 0; h < 2; ++h) {
          int row = wc * 64 + n * 16 + frow;
          bf[n][h] = *(const bf16x8*)&lds[b * 32768 + 16384 + row * 64 + ((h * 4 + fk) ^ (row & 7)) * 8];
        }
    }
    __builtin_amdgcn_s_setprio(1);
#pragma unroll
    for (int m = 0; m < 4; ++m)
#pragma unroll
      for (int n = 0; n < 4; ++n)
#pragma unroll
        for (int h = 0; h < 2; ++h)
          ac[m][n] = __builtin_amdgcn_mfma_f32_16x16x32_bf16(a[m][h], bf[n][h], ac[m][n], 0, 0, 0);
    __builtin_amdgcn_s_setprio(0);
    __builtin_amdgcn_sched_barrier(0);
  };

  stageB(0, 0); stageA(0, 0, 0); stageA(0, 1, 0);

  for (int t = 0; t < NT; ++t) {
    const int b = t & 1, nb = b ^ 1;
    const bool nx = (t + 1 < NT);
    SYNC_VM(2);                              // B(t), A0(t) landed; A1(t) may be in flight
    if (nx) stageB(t + 1, nb);
    bf16x8 bf[4][2];
    phase(b, 0, acc[0], bf, true);
    if (nx) { SYNC_VM(4); } else { SYNC_VM(0); }   // A1(t) landed
    if (nx) stageA(t + 1, 0, nb);
    phase(b, 1, acc[1], bf, false);
    if (nx) stageA(t + 1, 1, nb);
  }

  __hip_bfloat16* Yt = Y + (size_t)(e * kCap + mt * 256) * kD + nt * 256;
#pragma unroll
  for (int p = 0; p < 2; ++p)
#pragma unroll
    for (int m = 0; m < 4; ++m)
#pragma unroll
      for (int n = 0; n < 4; ++n)
#pragma unroll
        for (int r = 0; r < 4; ++r) {
          int row = wr * 128 + p * 64 + m * 16 + fk * 4 + r;
          int col = wc * 64 + n * 16 + frow;
          Yt[(size_t)row * kD + col] = __float2bfloat16(acc[p][m][n][r]);
        }
}

// ---------------- combine: out[t] = sum_k gate * y[slot] (deterministic gather, bf16 y) ----
__global__ __launch_bounds__(256)
void combine_kernel(const __hip_bfloat16* __restrict__ Y, const int* __restrict__ slot_of,
                    const float* __restrict__ gates, float* __restrict__ out) {
  int t = blockIdx.x;
  int dd = threadIdx.x * 4;
  int s0 = slot_of[2 * t], s1 = slot_of[2 * t + 1];
  float g0 = gates[2 * t], g1 = gates[2 * t + 1];
  float4 r = {0.f, 0.f, 0.f, 0.f};
  if (s0 >= 0) {
    bf16x4s v = *(const bf16x4s*)(Y + (size_t)s0 * kD + dd);
    r.x += g0 * __bfloat162float(v.v[0]); r.y += g0 * __bfloat162float(v.v[1]);
    r.z += g0 * __bfloat162float(v.v[2]); r.w += g0 * __bfloat162float(v.v[3]);
  }
  if (s1 >= 0) {
    bf16x4s v = *(const bf16x4s*)(Y + (size_t)s1 * kD + dd);
    r.x += g1 * __bfloat162float(v.v[0]); r.y += g1 * __bfloat162float(v.v[1]);
    r.z += g1 * __bfloat162float(v.v[2]); r.w += g1 * __bfloat162float(v.v[3]);
  }
  *(float4*)(out + (size_t)t * kD + dd) = r;
}

// ---------------- host launcher ----------------
extern "C" void kernel_launch(void* const* d_in, const int* in_sizes, int n_in,
                              void* d_out, int out_size, void* d_ws, size_t ws_size,
                              hipStream_t stream) {
  (void)in_sizes; (void)n_in; (void)out_size; (void)ws_size;
  const float* x  = (const float*)d_in[0];
  const float* rw = (const float*)d_in[1];
  const float* rb = (const float*)d_in[2];
  const float* w1 = (const float*)d_in[3];
  const float* w3 = (const float*)d_in[4];
  const float* w2 = (const float*)d_in[5];
  float* out = (float*)d_out;

  char* base = (char*)d_ws;
  size_t off = 0;
  auto alloc = [&](size_t bytes) -> char* {
    char* r = base + off;
    off += (bytes + 255) & ~(size_t)255;
    return r;
  };
  __hip_bfloat16* w1t = (__hip_bfloat16*)alloc((size_t)kE * kF * kD * 2);  // [E][F][D]
  __hip_bfloat16* w3t = (__hip_bfloat16*)alloc((size_t)kE * kF * kD * 2);  // [E][F][D]
  __hip_bfloat16* w2t = (__hip_bfloat16*)alloc((size_t)kE * kD * kF * 2);  // [E][D][F]
  __hip_bfloat16* buf = (__hip_bfloat16*)alloc((size_t)kECap * kD * 2);
  __hip_bfloat16* h   = (__hip_bfloat16*)alloc((size_t)kECap * kF * 2);
  __hip_bfloat16* y   = (__hip_bfloat16*)alloc((size_t)kECap * kD * 2);
  int*   e_idx    = (int*)alloc((size_t)kN * 4);
  float* gates    = (float*)alloc((size_t)kN * 4);
  int*   slot_of  = (int*)alloc((size_t)kN * 4);
  int*   token_of = (int*)alloc((size_t)kECap * 4);
  float* probs    = (float*)alloc((size_t)kT * 8 * 4);

  prep_kernel<<<kRouterBlocks + kT13Blocks + kT2Blocks, 256, 0, stream>>>(
      x, rw, rb, e_idx, gates, probs, w1, w3, w2, w1t, w3t, w2t);
  aux_kernel<<<1, 1024, 0, stream>>>(probs, e_idx, out + (size_t)kT * kD);
  rank_kernel<<<kE, 256, 0, stream>>>(e_idx, slot_of, token_of);
  gather_kernel<<<kECap, 64, 0, stream>>>(x, token_of, buf);
  gemm1_kernel<<<dim3(kF / 128, kCap / 256, kE), 512, 131072, stream>>>(buf, w1t, w3t, h);
  gemm2_kernel<<<dim3(kD / 256, kCap / 256, kE), 512, 131072, stream>>>(h, w2t, y);
  combine_kernel<<<kT, 256, 0, stream>>>(y, slot_of, gates, out);
}